// Round 9
// baseline (177.478 us; speedup 1.0000x reference)
//
#include <hip/hip_runtime.h>
#include <hip/hip_bf16.h>

#define NFEAT 256
#define NHID  128

typedef short s16x8 __attribute__((ext_vector_type(8)));
typedef float f32x4 __attribute__((ext_vector_type(4)));
typedef float f32x2 __attribute__((ext_vector_type(2)));

static __device__ __forceinline__ ushort bfbits(float f) {
  __hip_bfloat16 h = __float2bfloat16(f);
  return *reinterpret_cast<ushort*>(&h);
}

// ---------------------------------------------------------------------------
// W transpose+convert: Wt[n][k] = bf16(W[k][n])   (one-time, 32K elems)
// ---------------------------------------------------------------------------
__global__ __launch_bounds__(256) void wcvt_kernel(
    const float* __restrict__ W, ushort* __restrict__ Wt) {
  const int id = blockIdx.x * 256 + threadIdx.x;  // grid 128
  const int k = id >> 7, n = id & 127;            // coalesced read of W[k][n]
  Wt[n * NFEAT + k] = bfbits(W[id]);
}

// ---------------------------------------------------------------------------
// Fused GEMM || CSR-count.  LDS cut to 12KB (K-chunk 32) so occupancy is no
// longer LDS-capped (was 24KB -> 6 blocks/CU, 31% occ).  Count role: 8
// edges/thread, 8 independent with-return atomics in flight.  Roles are
// Bresenham-interleaved (1 count : ~2 gemm) so every CU holds a mix for the
// whole dispatch.
// ---------------------------------------------------------------------------
__global__ __launch_bounds__(256) void gemm_count_fused(
    const float* __restrict__ x, const ushort* __restrict__ Wt,
    ushort* __restrict__ sup, int n_nodes,
    const int* __restrict__ edst, int* __restrict__ counts,
    int* __restrict__ rank, int n_edges, int n_gemm, int n_count) {
  __shared__ ushort As[64 * 32];   // [r][k] swizzled, 4 KB
  __shared__ ushort Bs[128 * 32];  // [n][k] swizzled, 8 KB

  // proportional interleave of count (role 0) and gemm (role 1)
  const int idx = blockIdx.x;
  const long long total = (long long)n_gemm + n_count;
  const int c_lo = (int)((long long)idx * n_count / total);
  const int c_hi = (int)(((long long)idx + 1) * n_count / total);
  int role, sub;
  if (c_hi > c_lo) { role = 0; sub = c_lo; }
  else             { role = 1; sub = idx - c_hi; }

  if (role == 0) {
    // ---- CSR count + rank: 8 edges per thread ----
    const int e0 = sub * 2048 + threadIdx.x * 8;
    if (e0 + 7 < n_edges) {
      const int4 d0 = *(const int4*)(edst + e0);
      const int4 d1 = *(const int4*)(edst + e0 + 4);
      int r0 = atomicAdd(&counts[(uint)d0.x], 1);
      int r1 = atomicAdd(&counts[(uint)d0.y], 1);
      int r2 = atomicAdd(&counts[(uint)d0.z], 1);
      int r3 = atomicAdd(&counts[(uint)d0.w], 1);
      int r4 = atomicAdd(&counts[(uint)d1.x], 1);
      int r5 = atomicAdd(&counts[(uint)d1.y], 1);
      int r6 = atomicAdd(&counts[(uint)d1.z], 1);
      int r7 = atomicAdd(&counts[(uint)d1.w], 1);
      *(int4*)(rank + e0)     = make_int4(r0, r1, r2, r3);
      *(int4*)(rank + e0 + 4) = make_int4(r4, r5, r6, r7);
    } else {
      for (int e = e0; e < n_edges && e < e0 + 8; ++e)
        rank[e] = atomicAdd(&counts[(uint)edst[e]], 1);
    }
    return;
  }

  // ---- MFMA GEMM: BM=64 x NHID=128, K chunks of 32 ----
  const int t = threadIdx.x;
  const int wid = t >> 6;
  const int lane = t & 63;
  const int rowBase = sub * 64;
  if (rowBase >= n_nodes) return;

  f32x4 acc[4][2];
#pragma unroll
  for (int m = 0; m < 4; ++m)
#pragma unroll
    for (int n = 0; n < 2; ++n) acc[m][n] = (f32x4){0.f, 0.f, 0.f, 0.f};

  const float4* x4 = (const float4*)x;

  for (int kc = 0; kc < 8; ++kc) {
    __syncthreads();  // protect previous chunk's reads
    // stage A: 64 rows x 32 k (fp32 -> bf16), swizzled; 2 float4/thread
#pragma unroll
    for (int it = 0; it < 2; ++it) {
      const int i4 = t + it * 256;            // 0..511
      const int r = i4 >> 3, k4 = i4 & 7;
      const int row = rowBase + r;
      float4 v = make_float4(0.f, 0.f, 0.f, 0.f);
      if (row < n_nodes) v = x4[(size_t)row * (NFEAT / 4) + kc * 8 + k4];
      ushort4 h;
      h.x = bfbits(v.x); h.y = bfbits(v.y); h.z = bfbits(v.z); h.w = bfbits(v.w);
      int byte = (r << 6) + (k4 << 3);
      byte ^= (r & 7) << 4;
      *(ushort4*)((char*)As + byte) = h;
    }
    // stage B: 128 cols x 32 k from Wt (bf16), swizzled; 4 ushort4/thread
#pragma unroll
    for (int it = 0; it < 4; ++it) {
      const int i2 = t + it * 256;            // 0..1023
      const int col = i2 >> 3, k4 = i2 & 7;
      const ushort4 h = *(const ushort4*)(Wt + col * NFEAT + kc * 32 + k4 * 4);
      int byte = (col << 6) + (k4 << 3);
      byte ^= (col & 7) << 4;
      *(ushort4*)((char*)Bs + byte) = h;
    }
    __syncthreads();
    // one K=32 MFMA step
    const int k0 = (lane >> 4) * 8;
    s16x8 af[4], bfr[2];
#pragma unroll
    for (int m = 0; m < 4; ++m) {
      const int r = m * 16 + (lane & 15);
      int byte = (r << 6) + (k0 << 1);
      byte ^= (r & 7) << 4;
      af[m] = *(const s16x8*)((const char*)As + byte);
    }
#pragma unroll
    for (int n = 0; n < 2; ++n) {
      const int c = wid * 32 + n * 16 + (lane & 15);
      int byte = (c << 6) + (k0 << 1);
      byte ^= (c & 7) << 4;
      bfr[n] = *(const s16x8*)((const char*)Bs + byte);
    }
#pragma unroll
    for (int m = 0; m < 4; ++m)
#pragma unroll
      for (int n = 0; n < 2; ++n)
        acc[m][n] = __builtin_amdgcn_mfma_f32_16x16x32_bf16(af[m], bfr[n], acc[m][n], 0, 0, 0);
  }

  // C/D layout: col = lane&15, row = (lane>>4)*4 + reg   [m89-verified]
#pragma unroll
  for (int m = 0; m < 4; ++m) {
#pragma unroll
    for (int rr = 0; rr < 4; ++rr) {
      const int row = rowBase + m * 16 + (lane >> 4) * 4 + rr;
      if (row < n_nodes) {
#pragma unroll
        for (int n = 0; n < 2; ++n) {
          const int col = wid * 32 + n * 16 + (lane & 15);
          sup[(size_t)row * NHID + col] = bfbits(acc[m][n][rr]);
        }
      }
    }
  }
}

// ---------------------------------------------------------------------------
// Hierarchical exclusive scan over counts -> row_start
// ---------------------------------------------------------------------------
__global__ __launch_bounds__(256) void scan1_kernel(
    const int* __restrict__ in, int* __restrict__ exc,
    int* __restrict__ bsums, int n) {
  const int tid = threadIdx.x;
  const int lane = tid & 63, wid = tid >> 6;
  const int base = blockIdx.x * 1024 + tid * 4;
  int v0 = 0, v1 = 0, v2 = 0, v3 = 0;
  if (base + 3 < n) {
    int4 v = *(const int4*)(in + base);
    v0 = v.x; v1 = v.y; v2 = v.z; v3 = v.w;
  } else {
    if (base + 0 < n) v0 = in[base + 0];
    if (base + 1 < n) v1 = in[base + 1];
    if (base + 2 < n) v2 = in[base + 2];
  }
  const int tsum = v0 + v1 + v2 + v3;
  int t = tsum;
#pragma unroll
  for (int d = 1; d < 64; d <<= 1) {
    int u = __shfl_up(t, d);
    if (lane >= d) t += u;
  }
  __shared__ int wtot[4], wpre[4];
  if (lane == 63) wtot[wid] = t;
  __syncthreads();
  if (tid == 0) {
    int s = 0;
    for (int w = 0; w < 4; ++w) { wpre[w] = s; s += wtot[w]; }
    bsums[blockIdx.x] = s;
  }
  __syncthreads();
  const int off = (t - tsum) + wpre[wid];
  if (base + 0 < n) exc[base + 0] = off;
  if (base + 1 < n) exc[base + 1] = off + v0;
  if (base + 2 < n) exc[base + 2] = off + v0 + v1;
  if (base + 3 < n) exc[base + 3] = off + v0 + v1 + v2;
}

__global__ __launch_bounds__(256) void scan2_kernel(int* __restrict__ bsums, int nb) {
  const int tid = threadIdx.x;
  const int lane = tid & 63, wid = tid >> 6;
  const int v = (tid < nb) ? bsums[tid] : 0;
  int t = v;
#pragma unroll
  for (int d = 1; d < 64; d <<= 1) {
    int u = __shfl_up(t, d);
    if (lane >= d) t += u;
  }
  __shared__ int wtot[4], wpre[4];
  if (lane == 63) wtot[wid] = t;
  __syncthreads();
  if (tid == 0) {
    int s = 0;
    for (int w = 0; w < 4; ++w) { wpre[w] = s; s += wtot[w]; }
  }
  __syncthreads();
  const int exc = (t - v) + wpre[wid];
  if (tid < nb) bsums[tid] = exc;
}

__global__ __launch_bounds__(256) void scan3_kernel(
    const int* __restrict__ exc, const int* __restrict__ bsums,
    int* __restrict__ row_start, int n, int n_edges) {
  const int i = blockIdx.x * 256 + threadIdx.x;
  if (i < n) row_start[i] = exc[i] + bsums[i >> 10];
  if (i == 0) row_start[n] = n_edges;
}

__global__ __launch_bounds__(256) void fill_kernel(
    const int* __restrict__ esrc, const int* __restrict__ edst,
    const float* __restrict__ ew, const int* __restrict__ rank,
    const int* __restrict__ row_start, int2* __restrict__ packed, int n_edges) {
  const int e = blockIdx.x * 256 + threadIdx.x;
  if (e >= n_edges) return;
  const int pos = row_start[edst[e]] + rank[e];
  packed[pos] = make_int2(esrc[e], __float_as_int(ew[e]));
}

// ---------------------------------------------------------------------------
// Aggregation: 1 wave per node; lane owns 2 cols (uint = 2 bf16); SGPR-
// uniform packed loads; x8 unroll -> 8 independent gathers in flight with 4
// independent accumulator pairs.  Fused bias + ReLU, NT float2 store.
// ---------------------------------------------------------------------------
__global__ __launch_bounds__(256) void agg_kernel(
    const ushort* __restrict__ sup, const int2* __restrict__ packed,
    const int* __restrict__ row_start, const float* __restrict__ bias,
    float* __restrict__ out, int n_nodes) {
  const int node = blockIdx.x * 4 + (threadIdx.x >> 6);
  if (node >= n_nodes) return;
  const int lane = threadIdx.x & 63;
  const int start = __builtin_amdgcn_readfirstlane(row_start[node]);
  const int end   = __builtin_amdgcn_readfirstlane(row_start[node + 1]);

  float a0 = 0.f, a1 = 0.f, b0 = 0.f, b1 = 0.f;
  float c0 = 0.f, c1 = 0.f, d0 = 0.f, d1 = 0.f;
  int i = start;
  for (; i + 7 < end; i += 8) {
    const int2 e0 = packed[i + 0];
    const int2 e1 = packed[i + 1];
    const int2 e2 = packed[i + 2];
    const int2 e3 = packed[i + 3];
    const int2 e4 = packed[i + 4];
    const int2 e5 = packed[i + 5];
    const int2 e6 = packed[i + 6];
    const int2 e7 = packed[i + 7];
    const uint u0 = *(const uint*)(sup + ((size_t)(uint)e0.x << 7) + lane * 2);
    const uint u1 = *(const uint*)(sup + ((size_t)(uint)e1.x << 7) + lane * 2);
    const uint u2 = *(const uint*)(sup + ((size_t)(uint)e2.x << 7) + lane * 2);
    const uint u3 = *(const uint*)(sup + ((size_t)(uint)e3.x << 7) + lane * 2);
    const uint u4 = *(const uint*)(sup + ((size_t)(uint)e4.x << 7) + lane * 2);
    const uint u5 = *(const uint*)(sup + ((size_t)(uint)e5.x << 7) + lane * 2);
    const uint u6 = *(const uint*)(sup + ((size_t)(uint)e6.x << 7) + lane * 2);
    const uint u7 = *(const uint*)(sup + ((size_t)(uint)e7.x << 7) + lane * 2);
    const float w0 = __int_as_float(e0.y), w1 = __int_as_float(e1.y);
    const float w2 = __int_as_float(e2.y), w3 = __int_as_float(e3.y);
    const float w4 = __int_as_float(e4.y), w5 = __int_as_float(e5.y);
    const float w6 = __int_as_float(e6.y), w7 = __int_as_float(e7.y);
    a0 += __uint_as_float(u0 << 16) * w0 + __uint_as_float(u4 << 16) * w4;
    a1 += __uint_as_float(u0 & 0xffff0000u) * w0 + __uint_as_float(u4 & 0xffff0000u) * w4;
    b0 += __uint_as_float(u1 << 16) * w1 + __uint_as_float(u5 << 16) * w5;
    b1 += __uint_as_float(u1 & 0xffff0000u) * w1 + __uint_as_float(u5 & 0xffff0000u) * w5;
    c0 += __uint_as_float(u2 << 16) * w2 + __uint_as_float(u6 << 16) * w6;
    c1 += __uint_as_float(u2 & 0xffff0000u) * w2 + __uint_as_float(u6 & 0xffff0000u) * w6;
    d0 += __uint_as_float(u3 << 16) * w3 + __uint_as_float(u7 << 16) * w7;
    d1 += __uint_as_float(u3 & 0xffff0000u) * w3 + __uint_as_float(u7 & 0xffff0000u) * w7;
  }
  for (; i + 3 < end; i += 4) {
    const int2 e0 = packed[i + 0];
    const int2 e1 = packed[i + 1];
    const int2 e2 = packed[i + 2];
    const int2 e3 = packed[i + 3];
    const uint u0 = *(const uint*)(sup + ((size_t)(uint)e0.x << 7) + lane * 2);
    const uint u1 = *(const uint*)(sup + ((size_t)(uint)e1.x << 7) + lane * 2);
    const uint u2 = *(const uint*)(sup + ((size_t)(uint)e2.x << 7) + lane * 2);
    const uint u3 = *(const uint*)(sup + ((size_t)(uint)e3.x << 7) + lane * 2);
    const float w0 = __int_as_float(e0.y), w1 = __int_as_float(e1.y);
    const float w2 = __int_as_float(e2.y), w3 = __int_as_float(e3.y);
    a0 += __uint_as_float(u0 << 16) * w0 + __uint_as_float(u2 << 16) * w2;
    a1 += __uint_as_float(u0 & 0xffff0000u) * w0 + __uint_as_float(u2 & 0xffff0000u) * w2;
    b0 += __uint_as_float(u1 << 16) * w1 + __uint_as_float(u3 << 16) * w3;
    b1 += __uint_as_float(u1 & 0xffff0000u) * w1 + __uint_as_float(u3 & 0xffff0000u) * w3;
  }
  for (; i < end; ++i) {
    const int2 e0 = packed[i];
    const uint u0 = *(const uint*)(sup + ((size_t)(uint)e0.x << 7) + lane * 2);
    const float w0 = __int_as_float(e0.y);
    a0 += __uint_as_float(u0 << 16) * w0;
    a1 += __uint_as_float(u0 & 0xffff0000u) * w0;
  }

  const float2 bb = ((const float2*)bias)[lane];
  f32x2 r;
  r.x = fmaxf((a0 + b0) + (c0 + d0) + bb.x, 0.f);
  r.y = fmaxf((a1 + b1) + (c1 + d1) + bb.y, 0.f);
  __builtin_nontemporal_store(r, (f32x2*)out + (size_t)node * (NHID / 2) + lane);
}

// ---------------------------------------------------------------------------
// Fallback (ws too small): atomic scatter over bf16 support
// ---------------------------------------------------------------------------
__global__ __launch_bounds__(256) void scatter_bf16_kernel(
    const ushort* __restrict__ sup, const int* __restrict__ esrc,
    const int* __restrict__ edst, const float* __restrict__ ew,
    float* __restrict__ out, int n_edges) {
  const long long idx = (long long)blockIdx.x * 256 + threadIdx.x;
  const int e = (int)(idx >> 6);
  const int c2 = (int)(idx & 63);
  if (e >= n_edges) return;
  const int s = esrc[e];
  const int d = edst[e];
  const float wt = ew[e];
  const uint u = *(const uint*)(sup + (size_t)s * NHID + c2 * 2);
  float* drow = out + (size_t)d * NHID + c2 * 2;
  atomicAdd(drow + 0, __uint_as_float(u << 16) * wt);
  atomicAdd(drow + 1, __uint_as_float(u & 0xffff0000u) * wt);
}

__global__ __launch_bounds__(256) void bias_relu_kernel(
    float* __restrict__ out, const float* __restrict__ b, int n4) {
  const int i = blockIdx.x * 256 + threadIdx.x;
  if (i >= n4) return;
  float4 v = ((float4*)out)[i];
  const float4 bb = ((const float4*)b)[i & (NHID / 4 - 1)];
  v.x = fmaxf(v.x + bb.x, 0.f);
  v.y = fmaxf(v.y + bb.y, 0.f);
  v.z = fmaxf(v.z + bb.z, 0.f);
  v.w = fmaxf(v.w + bb.w, 0.f);
  ((float4*)out)[i] = v;
}

static inline size_t align_up(size_t v, size_t a) { return (v + a - 1) & ~(a - 1); }

extern "C" void kernel_launch(void* const* d_in, const int* in_sizes, int n_in,
                              void* d_out, int out_size, void* d_ws, size_t ws_size,
                              hipStream_t stream) {
  const float* x    = (const float*)d_in[0];
  const int*   esrc = (const int*)d_in[1];
  const int*   edst = (const int*)d_in[2];
  const float* ew   = (const float*)d_in[3];
  const float* W    = (const float*)d_in[4];
  const float* b    = (const float*)d_in[5];
  float* out = (float*)d_out;

  const int n_nodes = in_sizes[0] / NFEAT;
  const int n_edges = in_sizes[1];

  // workspace layout (~47 MB at N=100k, E=1.6M)
  char* ws = (char*)d_ws;
  size_t off = 0;
  ushort* sup     = (ushort*)(ws + off); off = align_up(off + (size_t)n_nodes * NHID * 2, 256);
  ushort* Wt      = (ushort*)(ws + off); off = align_up(off + (size_t)NFEAT * NHID * 2, 256);
  int* counts     = (int*)(ws + off);    off = align_up(off + (size_t)n_nodes * 4, 256);
  int* exc        = (int*)(ws + off);    off = align_up(off + (size_t)n_nodes * 4, 256);
  int* bsums      = (int*)(ws + off);    off = align_up(off + 1024 * 4, 256);
  int* row_start  = (int*)(ws + off);    off = align_up(off + ((size_t)n_nodes + 1) * 4, 256);
  int* rank       = (int*)(ws + off);    off = align_up(off + align_up((size_t)n_edges, 8) * 4, 256);
  int2* packed    = (int2*)(ws + off);   off = align_up(off + (size_t)n_edges * 8, 256);
  const bool csr_ok = (off <= ws_size) && (n_nodes <= 256 * 1024);

  const int n_gemm = (n_nodes + 63) / 64;

  if (csr_ok) {
    // 1) Wt = bf16(W^T); zero counters
    wcvt_kernel<<<(NFEAT * NHID) / 256, 256, 0, stream>>>(W, Wt);
    hipMemsetAsync(counts, 0, (size_t)n_nodes * 4, stream);

    // 2) fused GEMM || count+rank (proportionally interleaved)
    const int n_count = (n_edges + 2047) / 2048;
    gemm_count_fused<<<n_gemm + n_count, 256, 0, stream>>>(
        x, Wt, sup, n_nodes, edst, counts, rank, n_edges, n_gemm, n_count);

    // 3) scan + fill
    const int nb = (n_nodes + 1023) / 1024;
    scan1_kernel<<<nb, 256, 0, stream>>>(counts, exc, bsums, n_nodes);
    scan2_kernel<<<1, 256, 0, stream>>>(bsums, nb);
    scan3_kernel<<<(n_nodes + 255) / 256, 256, 0, stream>>>(exc, bsums, row_start, n_nodes, n_edges);
    fill_kernel<<<(n_edges + 255) / 256, 256, 0, stream>>>(esrc, edst, ew, rank, row_start, packed, n_edges);

    // 4) gather-sum + bias + relu
    agg_kernel<<<(n_nodes + 3) / 4, 256, 0, stream>>>(sup, packed, row_start, b, out, n_nodes);
  } else {
    // fallback: minimal-ws path (sup + Wt only), gemm role only
    wcvt_kernel<<<(NFEAT * NHID) / 256, 256, 0, stream>>>(W, Wt);
    gemm_count_fused<<<n_gemm, 256, 0, stream>>>(
        x, Wt, sup, n_nodes, edst, (int*)d_ws, (int*)d_ws, 0, n_gemm, 0);
    hipMemsetAsync(out, 0, (size_t)n_nodes * NHID * sizeof(float), stream);
    const long long threads = (long long)n_edges * 64;
    scatter_bf16_kernel<<<(int)((threads + 255) / 256), 256, 0, stream>>>(sup, esrc, edst, ew, out, n_edges);
    const int n4 = n_nodes * NHID / 4;
    bias_relu_kernel<<<(n4 + 255) / 256, 256, 0, stream>>>(out, b, n4);
  }
}

// Round 10
// 167.058 us; speedup vs baseline: 1.0624x; 1.0624x over previous
//
#include <hip/hip_runtime.h>
#include <hip/hip_bf16.h>

#define NFEAT 256
#define NHID  128
#define NPB   128   // nodes per bucket (dst >> 7)
#define BMAX  2048  // max buckets (n_nodes <= 256K)
#define DCAP  3072  // per-bucket LDS edge-list capacity (mean 2047, +22 sigma)

typedef short s16x8 __attribute__((ext_vector_type(8)));
typedef float f32x4 __attribute__((ext_vector_type(4)));
typedef float f32x2 __attribute__((ext_vector_type(2)));

static __device__ __forceinline__ ushort bfbits(float f) {
  __hip_bfloat16 h = __float2bfloat16(f);
  return *reinterpret_cast<ushort*>(&h);
}

// ---------------------------------------------------------------------------
// W transpose+convert: Wt[n][k] = bf16(W[k][n])
// ---------------------------------------------------------------------------
__global__ __launch_bounds__(256) void wcvt_kernel(
    const float* __restrict__ W, ushort* __restrict__ Wt) {
  const int id = blockIdx.x * 256 + threadIdx.x;
  const int k = id >> 7, n = id & 127;
  Wt[n * NFEAT + k] = bfbits(W[id]);
}

// ---------------------------------------------------------------------------
// Pass A: per-block bucket histogram via LDS atomics (no device atomics).
// histT[b*G + g] = #edges of block-chunk g landing in bucket b.
// ---------------------------------------------------------------------------
__global__ __launch_bounds__(256) void hist_kernel(
    const int* __restrict__ edst, int* __restrict__ histT,
    int n_edges, int B, int G, int chunk) {
  __shared__ int hist[BMAX];
  const int g = blockIdx.x;
  for (int b = threadIdx.x; b < B; b += 256) hist[b] = 0;
  __syncthreads();
  const int e0 = g * chunk;
  const int e1 = (e0 + chunk < n_edges) ? e0 + chunk : n_edges;
  for (int e = e0 + threadIdx.x; e < e1; e += 256)
    atomicAdd(&hist[(uint)edst[e] >> 7], 1);  // LDS atomic
  __syncthreads();
  for (int b = threadIdx.x; b < B; b += 256) histT[(size_t)b * G + g] = hist[b];
}

// ---------------------------------------------------------------------------
// Hierarchical exclusive scan (over histT, n = B*G <= 256K)
// ---------------------------------------------------------------------------
__global__ __launch_bounds__(256) void scan1_kernel(
    const int* __restrict__ in, int* __restrict__ exc,
    int* __restrict__ bsums, int n) {
  const int tid = threadIdx.x;
  const int lane = tid & 63, wid = tid >> 6;
  const int base = blockIdx.x * 1024 + tid * 4;
  int v0 = 0, v1 = 0, v2 = 0, v3 = 0;
  if (base + 3 < n) {
    int4 v = *(const int4*)(in + base);
    v0 = v.x; v1 = v.y; v2 = v.z; v3 = v.w;
  } else {
    if (base + 0 < n) v0 = in[base + 0];
    if (base + 1 < n) v1 = in[base + 1];
    if (base + 2 < n) v2 = in[base + 2];
  }
  const int tsum = v0 + v1 + v2 + v3;
  int t = tsum;
#pragma unroll
  for (int d = 1; d < 64; d <<= 1) {
    int u = __shfl_up(t, d);
    if (lane >= d) t += u;
  }
  __shared__ int wtot[4], wpre[4];
  if (lane == 63) wtot[wid] = t;
  __syncthreads();
  if (tid == 0) {
    int s = 0;
    for (int w = 0; w < 4; ++w) { wpre[w] = s; s += wtot[w]; }
    bsums[blockIdx.x] = s;
  }
  __syncthreads();
  const int off = (t - tsum) + wpre[wid];
  if (base + 0 < n) exc[base + 0] = off;
  if (base + 1 < n) exc[base + 1] = off + v0;
  if (base + 2 < n) exc[base + 2] = off + v0 + v1;
  if (base + 3 < n) exc[base + 3] = off + v0 + v1 + v2;
}

__global__ __launch_bounds__(256) void scan2_kernel(int* __restrict__ bsums, int nb) {
  const int tid = threadIdx.x;
  const int lane = tid & 63, wid = tid >> 6;
  const int v = (tid < nb) ? bsums[tid] : 0;
  int t = v;
#pragma unroll
  for (int d = 1; d < 64; d <<= 1) {
    int u = __shfl_up(t, d);
    if (lane >= d) t += u;
  }
  __shared__ int wtot[4], wpre[4];
  if (lane == 63) wtot[wid] = t;
  __syncthreads();
  if (tid == 0) {
    int s = 0;
    for (int w = 0; w < 4; ++w) { wpre[w] = s; s += wtot[w]; }
  }
  __syncthreads();
  const int exc = (t - v) + wpre[wid];
  if (tid < nb) bsums[tid] = exc;
}

// finalize base offsets in-place; emit bucket_start[]
__global__ __launch_bounds__(256) void scan3_kernel(
    int* __restrict__ exc, const int* __restrict__ bsums,
    int* __restrict__ bucket_start, int n, int G, int B, int n_edges) {
  const int i = blockIdx.x * 256 + threadIdx.x;
  if (i < n) {
    const int v = exc[i] + bsums[i >> 10];
    exc[i] = v;
    if (i % G == 0) bucket_start[i / G] = v;
  }
  if (i == 0) bucket_start[B] = n_edges;
}

// ---------------------------------------------------------------------------
// Fused: bucket-scatter (role 0, LDS cursors only) || MFMA GEMM (role 1,
// R8's conflict-free K=64 tile).  Proportional interleave for co-residency.
// packed2 entry: .x = src | (dst&127)<<18  (src < 2^18), .y = w (f32 bits)
// ---------------------------------------------------------------------------
__global__ __launch_bounds__(256) void gemm_scatter_fused(
    const float* __restrict__ x, const ushort* __restrict__ Wt,
    ushort* __restrict__ sup, int n_nodes,
    const int* __restrict__ esrc, const int* __restrict__ edst,
    const float* __restrict__ ew, const int* __restrict__ base,
    int2* __restrict__ packed2, int n_edges, int B, int G, int chunk,
    int n_gemm) {
  __shared__ ushort As[64 * 64];   // 8 KB (scatter role aliases this as cursors)
  __shared__ ushort Bs[128 * 64];  // 16 KB

  const int idx = blockIdx.x;
  const long long total = (long long)n_gemm + G;
  const int c_lo = (int)((long long)idx * G / total);
  const int c_hi = (int)(((long long)idx + 1) * G / total);
  int role, sub;
  if (c_hi > c_lo) { role = 0; sub = c_lo; }
  else             { role = 1; sub = idx - c_hi; }

  if (role == 0) {
    // ---- bucket scatter: LDS cursors seeded from scanned bases ----
    int* cursor = (int*)As;  // 2048 ints = 8 KB
    const int g = sub;
    for (int b = threadIdx.x; b < B; b += 256) cursor[b] = base[(size_t)b * G + g];
    __syncthreads();
    const int e0 = g * chunk;
    const int e1 = (e0 + chunk < n_edges) ? e0 + chunk : n_edges;
    for (int e = e0 + threadIdx.x; e < e1; e += 256) {
      const int dst = edst[e];
      const int src = esrc[e];
      const float w = ew[e];
      const int pos = atomicAdd(&cursor[(uint)dst >> 7], 1);  // LDS atomic
      packed2[pos] = make_int2(src | ((dst & (NPB - 1)) << 18), __float_as_int(w));
    }
    return;
  }

  // ---- MFMA GEMM: BM=64 x NHID=128, K chunks of 64 ----
  const int t = threadIdx.x;
  const int wid = t >> 6;
  const int lane = t & 63;
  const int rowBase = sub * 64;
  if (rowBase >= n_nodes) return;

  f32x4 acc[4][2];
#pragma unroll
  for (int m = 0; m < 4; ++m)
#pragma unroll
    for (int n = 0; n < 2; ++n) acc[m][n] = (f32x4){0.f, 0.f, 0.f, 0.f};

  const float4* x4 = (const float4*)x;

  for (int kc = 0; kc < 4; ++kc) {
    __syncthreads();
#pragma unroll
    for (int it = 0; it < 4; ++it) {
      const int i4 = t + it * 256;
      const int r = i4 >> 4, k4 = i4 & 15;
      const int row = rowBase + r;
      float4 v = make_float4(0.f, 0.f, 0.f, 0.f);
      if (row < n_nodes) v = x4[(size_t)row * (NFEAT / 4) + kc * 16 + k4];
      ushort4 h;
      h.x = bfbits(v.x); h.y = bfbits(v.y); h.z = bfbits(v.z); h.w = bfbits(v.w);
      int byte = (r << 7) + (k4 << 3);
      byte ^= (r & 7) << 4;
      *(ushort4*)((char*)As + byte) = h;
    }
#pragma unroll
    for (int it = 0; it < 8; ++it) {
      const int i2 = t + it * 256;
      const int col = i2 >> 4, k4 = i2 & 15;
      const ushort4 h = *(const ushort4*)(Wt + col * NFEAT + kc * 64 + k4 * 4);
      int byte = (col << 7) + (k4 << 3);
      byte ^= (col & 7) << 4;
      *(ushort4*)((char*)Bs + byte) = h;
    }
    __syncthreads();
#pragma unroll
    for (int ks = 0; ks < 2; ++ks) {
      const int k0 = ks * 32 + (lane >> 4) * 8;
      s16x8 af[4], bfr[2];
#pragma unroll
      for (int m = 0; m < 4; ++m) {
        const int r = m * 16 + (lane & 15);
        int byte = (r << 7) + (k0 << 1);
        byte ^= (r & 7) << 4;
        af[m] = *(const s16x8*)((const char*)As + byte);
      }
#pragma unroll
      for (int n = 0; n < 2; ++n) {
        const int c = wid * 32 + n * 16 + (lane & 15);
        int byte = (c << 7) + (k0 << 1);
        byte ^= (c & 7) << 4;
        bfr[n] = *(const s16x8*)((const char*)Bs + byte);
      }
#pragma unroll
      for (int m = 0; m < 4; ++m)
#pragma unroll
        for (int n = 0; n < 2; ++n)
          acc[m][n] = __builtin_amdgcn_mfma_f32_16x16x32_bf16(af[m], bfr[n], acc[m][n], 0, 0, 0);
    }
  }

#pragma unroll
  for (int m = 0; m < 4; ++m) {
#pragma unroll
    for (int rr = 0; rr < 4; ++rr) {
      const int row = rowBase + m * 16 + (lane >> 4) * 4 + rr;
      if (row < n_nodes) {
#pragma unroll
        for (int n = 0; n < 2; ++n) {
          const int col = wid * 32 + n * 16 + (lane & 15);
          sup[(size_t)row * NHID + col] = bfbits(acc[m][n][rr]);
        }
      }
    }
  }
}

// ---------------------------------------------------------------------------
// Pass D: per-bucket aggregation.  Build node-grouped edge list in LDS
// (LDS-atomic rank + 128-wide shuffle scan + LDS scatter), then per-node
// x8-unrolled gather-sum over sup rows.  Fused bias+ReLU, NT store.
// ---------------------------------------------------------------------------
__global__ __launch_bounds__(256) void bucket_agg_kernel(
    const ushort* __restrict__ sup, const int2* __restrict__ packed2,
    const int* __restrict__ bucket_start, const float* __restrict__ bias,
    float* __restrict__ out, int n_nodes) {
  __shared__ int2 list[DCAP];   // 24 KB
  __shared__ int cnt[NPB];
  __shared__ int st[NPB];
  __shared__ int w0tot;
  const int tid = threadIdx.x;
  const int b = blockIdx.x;
  const int s0 = bucket_start[b];
  const int s1 = bucket_start[b + 1];
  const int m = s1 - s0;
  const int mm = (m < DCAP) ? m : DCAP;

  if (tid < NPB) cnt[tid] = 0;
  __syncthreads();

  // phase 1: read + LDS-atomic rank + register stash (static indices)
  int2 ev[12]; int rv[12];
#pragma unroll
  for (int j = 0; j < 12; ++j) {
    const int i = j * 256 + tid;
    if (i < mm) {
      const int2 e = packed2[s0 + i];
      ev[j] = e;
      rv[j] = atomicAdd(&cnt[((uint)e.x >> 18) & (NPB - 1)], 1);
    }
  }
  __syncthreads();

  // exclusive scan of cnt[128] (2 waves via shuffles)
  {
    const int v = (tid < NPB) ? cnt[tid] : 0;
    int t = v;
#pragma unroll
    for (int d = 1; d < 64; d <<= 1) {
      int u = __shfl_up(t, d);
      if ((tid & 63) >= d) t += u;
    }
    if (tid == 63) w0tot = t;  // total of nodes 0..63
    __syncthreads();
    if (tid < NPB) st[tid] = (t - v) + ((tid >= 64) ? w0tot : 0);
    __syncthreads();
  }

  // phase 2: scatter stash into grouped LDS list
#pragma unroll
  for (int j = 0; j < 12; ++j) {
    const int i = j * 256 + tid;
    if (i < mm) {
      const int dl = ((uint)ev[j].x >> 18) & (NPB - 1);
      list[st[dl] + rv[j]] = ev[j];
    }
  }
  __syncthreads();

  // phase 3: per-node gather-sum (1 wave per node, lane owns 2 cols)
  const int wav = tid >> 6, lane = tid & 63;
  for (int nl = wav; nl < NPB; nl += 4) {
    const int node = b * NPB + nl;
    if (node >= n_nodes) break;
    const int ls = st[nl];
    const int le = ls + cnt[nl];
    float a0 = 0.f, a1 = 0.f, b0 = 0.f, b1 = 0.f;
    float c0 = 0.f, c1 = 0.f, d0 = 0.f, d1 = 0.f;
    int i = ls;
    for (; i + 7 < le; i += 8) {
      const int2 e0 = list[i + 0], e1 = list[i + 1], e2 = list[i + 2], e3 = list[i + 3];
      const int2 e4 = list[i + 4], e5 = list[i + 5], e6 = list[i + 6], e7 = list[i + 7];
      const uint u0 = *(const uint*)(sup + ((size_t)((uint)e0.x & 0x3FFFFu) << 7) + lane * 2);
      const uint u1 = *(const uint*)(sup + ((size_t)((uint)e1.x & 0x3FFFFu) << 7) + lane * 2);
      const uint u2 = *(const uint*)(sup + ((size_t)((uint)e2.x & 0x3FFFFu) << 7) + lane * 2);
      const uint u3 = *(const uint*)(sup + ((size_t)((uint)e3.x & 0x3FFFFu) << 7) + lane * 2);
      const uint u4 = *(const uint*)(sup + ((size_t)((uint)e4.x & 0x3FFFFu) << 7) + lane * 2);
      const uint u5 = *(const uint*)(sup + ((size_t)((uint)e5.x & 0x3FFFFu) << 7) + lane * 2);
      const uint u6 = *(const uint*)(sup + ((size_t)((uint)e6.x & 0x3FFFFu) << 7) + lane * 2);
      const uint u7 = *(const uint*)(sup + ((size_t)((uint)e7.x & 0x3FFFFu) << 7) + lane * 2);
      const float w0 = __int_as_float(e0.y), w1 = __int_as_float(e1.y);
      const float w2 = __int_as_float(e2.y), w3 = __int_as_float(e3.y);
      const float w4 = __int_as_float(e4.y), w5 = __int_as_float(e5.y);
      const float w6 = __int_as_float(e6.y), w7 = __int_as_float(e7.y);
      a0 += __uint_as_float(u0 << 16) * w0 + __uint_as_float(u4 << 16) * w4;
      a1 += __uint_as_float(u0 & 0xffff0000u) * w0 + __uint_as_float(u4 & 0xffff0000u) * w4;
      b0 += __uint_as_float(u1 << 16) * w1 + __uint_as_float(u5 << 16) * w5;
      b1 += __uint_as_float(u1 & 0xffff0000u) * w1 + __uint_as_float(u5 & 0xffff0000u) * w5;
      c0 += __uint_as_float(u2 << 16) * w2 + __uint_as_float(u6 << 16) * w6;
      c1 += __uint_as_float(u2 & 0xffff0000u) * w2 + __uint_as_float(u6 & 0xffff0000u) * w6;
      d0 += __uint_as_float(u3 << 16) * w3 + __uint_as_float(u7 << 16) * w7;
      d1 += __uint_as_float(u3 & 0xffff0000u) * w3 + __uint_as_float(u7 & 0xffff0000u) * w7;
    }
    for (; i < le; ++i) {
      const int2 e0 = list[i];
      const uint u0 = *(const uint*)(sup + ((size_t)((uint)e0.x & 0x3FFFFu) << 7) + lane * 2);
      const float w0 = __int_as_float(e0.y);
      a0 += __uint_as_float(u0 << 16) * w0;
      a1 += __uint_as_float(u0 & 0xffff0000u) * w0;
    }
    // overflow tail (m > DCAP: ~never; correctness guard)
    for (int i2 = DCAP; i2 < m; ++i2) {
      const int2 e0 = packed2[s0 + i2];
      if ((((uint)e0.x >> 18) & (NPB - 1)) == (uint)nl) {
        const uint u0 = *(const uint*)(sup + ((size_t)((uint)e0.x & 0x3FFFFu) << 7) + lane * 2);
        const float w0 = __int_as_float(e0.y);
        a0 += __uint_as_float(u0 << 16) * w0;
        a1 += __uint_as_float(u0 & 0xffff0000u) * w0;
      }
    }
    const float2 bb = ((const float2*)bias)[lane];
    f32x2 r;
    r.x = fmaxf((a0 + b0) + (c0 + d0) + bb.x, 0.f);
    r.y = fmaxf((a1 + b1) + (c1 + d1) + bb.y, 0.f);
    __builtin_nontemporal_store(r, (f32x2*)out + (size_t)node * (NHID / 2) + lane);
  }
}

// ---------------------------------------------------------------------------
// Fallback (ws too small): atomic scatter over bf16 support
// ---------------------------------------------------------------------------
__global__ __launch_bounds__(256) void scatter_bf16_kernel(
    const ushort* __restrict__ sup, const int* __restrict__ esrc,
    const int* __restrict__ edst, const float* __restrict__ ew,
    float* __restrict__ out, int n_edges) {
  const long long idx = (long long)blockIdx.x * 256 + threadIdx.x;
  const int e = (int)(idx >> 6);
  const int c2 = (int)(idx & 63);
  if (e >= n_edges) return;
  const int s = esrc[e];
  const int d = edst[e];
  const float wt = ew[e];
  const uint u = *(const uint*)(sup + (size_t)s * NHID + c2 * 2);
  float* drow = out + (size_t)d * NHID + c2 * 2;
  atomicAdd(drow + 0, __uint_as_float(u << 16) * wt);
  atomicAdd(drow + 1, __uint_as_float(u & 0xffff0000u) * wt);
}

__global__ __launch_bounds__(256) void bias_relu_kernel(
    float* __restrict__ out, const float* __restrict__ b, int n4) {
  const int i = blockIdx.x * 256 + threadIdx.x;
  if (i >= n4) return;
  float4 v = ((float4*)out)[i];
  const float4 bb = ((const float4*)b)[i & (NHID / 4 - 1)];
  v.x = fmaxf(v.x + bb.x, 0.f);
  v.y = fmaxf(v.y + bb.y, 0.f);
  v.z = fmaxf(v.z + bb.z, 0.f);
  v.w = fmaxf(v.w + bb.w, 0.f);
  ((float4*)out)[i] = v;
}

static inline size_t align_up(size_t v, size_t a) { return (v + a - 1) & ~(a - 1); }

extern "C" void kernel_launch(void* const* d_in, const int* in_sizes, int n_in,
                              void* d_out, int out_size, void* d_ws, size_t ws_size,
                              hipStream_t stream) {
  const float* x    = (const float*)d_in[0];
  const int*   esrc = (const int*)d_in[1];
  const int*   edst = (const int*)d_in[2];
  const float* ew   = (const float*)d_in[3];
  const float* W    = (const float*)d_in[4];
  const float* b    = (const float*)d_in[5];
  float* out = (float*)d_out;

  const int n_nodes = in_sizes[0] / NFEAT;
  const int n_edges = in_sizes[1];

  // bucket geometry: B buckets of NPB nodes; G scatter chunks, B*G <= 256K
  const int B = (n_nodes + NPB - 1) / NPB;
  int G = (n_edges + 8191) / 8192;
  const int Gmax = (256 * 1024) / (B > 0 ? B : 1);
  if (G > Gmax) G = Gmax;
  if (G < 1) G = 1;
  const int chunk = (int)align_up((size_t)(n_edges + G - 1) / G, 256);
  G = (n_edges + chunk - 1) / chunk;  // recompute after rounding

  // workspace layout (~40 MB at N=100k, E=1.6M)
  char* ws = (char*)d_ws;
  size_t off = 0;
  ushort* sup       = (ushort*)(ws + off); off = align_up(off + (size_t)n_nodes * NHID * 2, 256);
  ushort* Wt        = (ushort*)(ws + off); off = align_up(off + (size_t)NFEAT * NHID * 2, 256);
  int* histT        = (int*)(ws + off);    off = align_up(off + (size_t)B * G * 4, 256);
  int* exc          = (int*)(ws + off);    off = align_up(off + (size_t)B * G * 4, 256);
  int* bsums        = (int*)(ws + off);    off = align_up(off + 1024 * 4, 256);
  int* bucket_start = (int*)(ws + off);    off = align_up(off + ((size_t)B + 1) * 4, 256);
  int2* packed2     = (int2*)(ws + off);   off = align_up(off + (size_t)n_edges * 8, 256);
  const bool csr_ok = (off <= ws_size) && (n_nodes <= 256 * 1024) && (B <= BMAX);

  const int n_gemm = (n_nodes + 63) / 64;

  if (csr_ok) {
    // 1) Wt = bf16(W^T)
    wcvt_kernel<<<(NFEAT * NHID) / 256, 256, 0, stream>>>(W, Wt);

    // 2) bucket histogram (LDS atomics only)
    hist_kernel<<<G, 256, 0, stream>>>(edst, histT, n_edges, B, G, chunk);

    // 3) scan -> per-(bucket,chunk) bases + bucket_start
    const int n_scan = B * G;
    const int nb = (n_scan + 1023) / 1024;
    scan1_kernel<<<nb, 256, 0, stream>>>(histT, exc, bsums, n_scan);
    scan2_kernel<<<1, 256, 0, stream>>>(bsums, nb);
    scan3_kernel<<<(n_scan + 255) / 256, 256, 0, stream>>>(exc, bsums, bucket_start, n_scan, G, B, n_edges);

    // 4) fused bucket-scatter || MFMA GEMM
    gemm_scatter_fused<<<n_gemm + G, 256, 0, stream>>>(
        x, Wt, sup, n_nodes, esrc, edst, ew, exc, packed2,
        n_edges, B, G, chunk, n_gemm);

    // 5) per-bucket LDS-CSR build + gather-sum + bias + relu
    bucket_agg_kernel<<<B, 256, 0, stream>>>(sup, packed2, bucket_start, b, out, n_nodes);
  } else {
    // fallback: minimal-ws path (sup + Wt only), gemm role only
    wcvt_kernel<<<(NFEAT * NHID) / 256, 256, 0, stream>>>(W, Wt);
    gemm_scatter_fused<<<n_gemm, 256, 0, stream>>>(
        x, Wt, sup, n_nodes, esrc, edst, ew, (int*)d_ws, (int2*)d_ws,
        0, 1, 0, 1, n_gemm);
    hipMemsetAsync(out, 0, (size_t)n_nodes * NHID * sizeof(float), stream);
    const long long threads = (long long)n_edges * 64;
    scatter_bf16_kernel<<<(int)((threads + 255) / 256), 256, 0, stream>>>(sup, esrc, edst, ew, out, n_edges);
    const int n4 = n_nodes * NHID / 4;
    bias_relu_kernel<<<(n4 + 255) / 256, 256, 0, stream>>>(out, b, n4);
  }
}

// Round 11
// 146.489 us; speedup vs baseline: 1.2115x; 1.1404x over previous
//
#include <hip/hip_runtime.h>
#include <hip/hip_bf16.h>

#define NFEAT 256
#define NHID  128
#define NPB   128   // nodes per bucket (dst >> 7)
#define BMAX  2048  // max buckets (n_nodes <= 256K)

typedef short s16x8 __attribute__((ext_vector_type(8)));
typedef float f32x4 __attribute__((ext_vector_type(4)));
typedef float f32x2 __attribute__((ext_vector_type(2)));

static __device__ __forceinline__ ushort bfbits(float f) {
  __hip_bfloat16 h = __float2bfloat16(f);
  return *reinterpret_cast<ushort*>(&h);
}

// ---------------------------------------------------------------------------
// W transpose+convert: Wt[n][k] = bf16(W[k][n])
// ---------------------------------------------------------------------------
__global__ __launch_bounds__(256) void wcvt_kernel(
    const float* __restrict__ W, ushort* __restrict__ Wt) {
  const int id = blockIdx.x * 256 + threadIdx.x;
  const int k = id >> 7, n = id & 127;
  Wt[n * NFEAT + k] = bfbits(W[id]);
}

// ---------------------------------------------------------------------------
// Pass A: per-block bucket histogram via LDS atomics (no device atomics).
// histT[b*G + g] = #edges of block-chunk g landing in bucket b.
// ---------------------------------------------------------------------------
__global__ __launch_bounds__(256) void hist_kernel(
    const int* __restrict__ edst, int* __restrict__ histT,
    int n_edges, int B, int G, int chunk) {
  __shared__ int hist[BMAX];
  const int g = blockIdx.x;
  for (int b = threadIdx.x; b < B; b += 256) hist[b] = 0;
  __syncthreads();
  const int e0 = g * chunk;
  const int e1 = (e0 + chunk < n_edges) ? e0 + chunk : n_edges;
  for (int e = e0 + threadIdx.x; e < e1; e += 256)
    atomicAdd(&hist[(uint)edst[e] >> 7], 1);  // LDS atomic
  __syncthreads();
  for (int b = threadIdx.x; b < B; b += 256) histT[(size_t)b * G + g] = hist[b];
}

// ---------------------------------------------------------------------------
// Hierarchical exclusive scan (over histT, n = B*G <= 256K)
// ---------------------------------------------------------------------------
__global__ __launch_bounds__(256) void scan1_kernel(
    const int* __restrict__ in, int* __restrict__ exc,
    int* __restrict__ bsums, int n) {
  const int tid = threadIdx.x;
  const int lane = tid & 63, wid = tid >> 6;
  const int base = blockIdx.x * 1024 + tid * 4;
  int v0 = 0, v1 = 0, v2 = 0, v3 = 0;
  if (base + 3 < n) {
    int4 v = *(const int4*)(in + base);
    v0 = v.x; v1 = v.y; v2 = v.z; v3 = v.w;
  } else {
    if (base + 0 < n) v0 = in[base + 0];
    if (base + 1 < n) v1 = in[base + 1];
    if (base + 2 < n) v2 = in[base + 2];
  }
  const int tsum = v0 + v1 + v2 + v3;
  int t = tsum;
#pragma unroll
  for (int d = 1; d < 64; d <<= 1) {
    int u = __shfl_up(t, d);
    if (lane >= d) t += u;
  }
  __shared__ int wtot[4], wpre[4];
  if (lane == 63) wtot[wid] = t;
  __syncthreads();
  if (tid == 0) {
    int s = 0;
    for (int w = 0; w < 4; ++w) { wpre[w] = s; s += wtot[w]; }
    bsums[blockIdx.x] = s;
  }
  __syncthreads();
  const int off = (t - tsum) + wpre[wid];
  if (base + 0 < n) exc[base + 0] = off;
  if (base + 1 < n) exc[base + 1] = off + v0;
  if (base + 2 < n) exc[base + 2] = off + v0 + v1;
  if (base + 3 < n) exc[base + 3] = off + v0 + v1 + v2;
}

__global__ __launch_bounds__(256) void scan2_kernel(int* __restrict__ bsums, int nb) {
  const int tid = threadIdx.x;
  const int lane = tid & 63, wid = tid >> 6;
  const int v = (tid < nb) ? bsums[tid] : 0;
  int t = v;
#pragma unroll
  for (int d = 1; d < 64; d <<= 1) {
    int u = __shfl_up(t, d);
    if (lane >= d) t += u;
  }
  __shared__ int wtot[4], wpre[4];
  if (lane == 63) wtot[wid] = t;
  __syncthreads();
  if (tid == 0) {
    int s = 0;
    for (int w = 0; w < 4; ++w) { wpre[w] = s; s += wtot[w]; }
  }
  __syncthreads();
  const int exc = (t - v) + wpre[wid];
  if (tid < nb) bsums[tid] = exc;
}

// finalize base offsets in-place; emit bucket_start[]
__global__ __launch_bounds__(256) void scan3_kernel(
    int* __restrict__ exc, const int* __restrict__ bsums,
    int* __restrict__ bucket_start, int n, int G, int B, int n_edges) {
  const int i = blockIdx.x * 256 + threadIdx.x;
  if (i < n) {
    const int v = exc[i] + bsums[i >> 10];
    exc[i] = v;
    if (i % G == 0) bucket_start[i / G] = v;
  }
  if (i == 0) bucket_start[B] = n_edges;
}

// ---------------------------------------------------------------------------
// Fused: bucket-scatter (role 0, LDS cursors only) || MFMA GEMM (role 1).
// packed2 entry: .x = src | (dst&127)<<18  (src < 2^18), .y = w (f32 bits)
// ---------------------------------------------------------------------------
__global__ __launch_bounds__(256) void gemm_scatter_fused(
    const float* __restrict__ x, const ushort* __restrict__ Wt,
    ushort* __restrict__ sup, int n_nodes,
    const int* __restrict__ esrc, const int* __restrict__ edst,
    const float* __restrict__ ew, const int* __restrict__ base,
    int2* __restrict__ packed2, int n_edges, int B, int G, int chunk,
    int n_gemm) {
  __shared__ ushort As[64 * 64];   // 8 KB (scatter role aliases this as cursors)
  __shared__ ushort Bs[128 * 64];  // 16 KB

  const int idx = blockIdx.x;
  const long long total = (long long)n_gemm + G;
  const int c_lo = (int)((long long)idx * G / total);
  const int c_hi = (int)(((long long)idx + 1) * G / total);
  int role, sub;
  if (c_hi > c_lo) { role = 0; sub = c_lo; }
  else             { role = 1; sub = idx - c_hi; }

  if (role == 0) {
    // ---- bucket scatter: LDS cursors seeded from scanned bases ----
    int* cursor = (int*)As;  // up to 2048 ints = 8 KB
    const int g = sub;
    for (int b = threadIdx.x; b < B; b += 256) cursor[b] = base[(size_t)b * G + g];
    __syncthreads();
    const int e0 = g * chunk;
    const int e1 = (e0 + chunk < n_edges) ? e0 + chunk : n_edges;
    for (int e = e0 + threadIdx.x; e < e1; e += 256) {
      const int dst = edst[e];
      const int src = esrc[e];
      const float w = ew[e];
      const int pos = atomicAdd(&cursor[(uint)dst >> 7], 1);  // LDS atomic
      packed2[pos] = make_int2(src | ((dst & (NPB - 1)) << 18), __float_as_int(w));
    }
    return;
  }

  // ---- MFMA GEMM: BM=64 x NHID=128, K chunks of 64 ----
  const int t = threadIdx.x;
  const int wid = t >> 6;
  const int lane = t & 63;
  const int rowBase = sub * 64;
  if (rowBase >= n_nodes) return;

  f32x4 acc[4][2];
#pragma unroll
  for (int m = 0; m < 4; ++m)
#pragma unroll
    for (int n = 0; n < 2; ++n) acc[m][n] = (f32x4){0.f, 0.f, 0.f, 0.f};

  const float4* x4 = (const float4*)x;

  for (int kc = 0; kc < 4; ++kc) {
    __syncthreads();
#pragma unroll
    for (int it = 0; it < 4; ++it) {
      const int i4 = t + it * 256;
      const int r = i4 >> 4, k4 = i4 & 15;
      const int row = rowBase + r;
      float4 v = make_float4(0.f, 0.f, 0.f, 0.f);
      if (row < n_nodes) v = x4[(size_t)row * (NFEAT / 4) + kc * 16 + k4];
      ushort4 h;
      h.x = bfbits(v.x); h.y = bfbits(v.y); h.z = bfbits(v.z); h.w = bfbits(v.w);
      int byte = (r << 7) + (k4 << 3);
      byte ^= (r & 7) << 4;
      *(ushort4*)((char*)As + byte) = h;
    }
#pragma unroll
    for (int it = 0; it < 8; ++it) {
      const int i2 = t + it * 256;
      const int col = i2 >> 4, k4 = i2 & 15;
      const ushort4 h = *(const ushort4*)(Wt + col * NFEAT + kc * 64 + k4 * 4);
      int byte = (col << 7) + (k4 << 3);
      byte ^= (col & 7) << 4;
      *(ushort4*)((char*)Bs + byte) = h;
    }
    __syncthreads();
#pragma unroll
    for (int ks = 0; ks < 2; ++ks) {
      const int k0 = ks * 32 + (lane >> 4) * 8;
      s16x8 af[4], bfr[2];
#pragma unroll
      for (int m = 0; m < 4; ++m) {
        const int r = m * 16 + (lane & 15);
        int byte = (r << 7) + (k0 << 1);
        byte ^= (r & 7) << 4;
        af[m] = *(const s16x8*)((const char*)As + byte);
      }
#pragma unroll
      for (int n = 0; n < 2; ++n) {
        const int c = wid * 32 + n * 16 + (lane & 15);
        int byte = (c << 7) + (k0 << 1);
        byte ^= (c & 7) << 4;
        bfr[n] = *(const s16x8*)((const char*)Bs + byte);
      }
#pragma unroll
      for (int m = 0; m < 4; ++m)
#pragma unroll
        for (int n = 0; n < 2; ++n)
          acc[m][n] = __builtin_amdgcn_mfma_f32_16x16x32_bf16(af[m], bfr[n], acc[m][n], 0, 0, 0);
    }
  }

#pragma unroll
  for (int m = 0; m < 4; ++m) {
#pragma unroll
    for (int rr = 0; rr < 4; ++rr) {
      const int row = rowBase + m * 16 + (lane >> 4) * 4 + rr;
      if (row < n_nodes) {
#pragma unroll
        for (int n = 0; n < 2; ++n) {
          const int col = wid * 32 + n * 16 + (lane & 15);
          sup[(size_t)row * NHID + col] = bfbits(acc[m][n][rr]);
        }
      }
    }
  }
}

// ---------------------------------------------------------------------------
// Pass C: per-bucket node-grouping (two sweeps, LDS count + scan + cursor
// scatter), writing node-grouped packedN + per-node row_start to GLOBAL.
// Gather then runs at full TLP in the separate agg kernel.
// ---------------------------------------------------------------------------
__global__ __launch_bounds__(256) void bucket_build_kernel(
    const int2* __restrict__ packed2, const int* __restrict__ bucket_start,
    int2* __restrict__ packedN, int* __restrict__ row_start,
    int n_nodes, int n_edges) {
  __shared__ int cnt[NPB];
  __shared__ int st[NPB];
  __shared__ int cur[NPB];
  __shared__ int w0tot;
  const int tid = threadIdx.x;
  const int b = blockIdx.x;
  const int s0 = bucket_start[b];
  const int s1 = bucket_start[b + 1];
  const int m = s1 - s0;

  if (tid < NPB) cnt[tid] = 0;
  __syncthreads();

  // sweep 1: count per local node
  for (int i = tid; i < m; i += 256)
    atomicAdd(&cnt[((uint)packed2[s0 + i].x >> 18) & (NPB - 1)], 1);
  __syncthreads();

  // exclusive scan of cnt[128]
  {
    const int v = (tid < NPB) ? cnt[tid] : 0;
    int t = v;
#pragma unroll
    for (int d = 1; d < 64; d <<= 1) {
      int u = __shfl_up(t, d);
      if ((tid & 63) >= d) t += u;
    }
    if (tid == 63) w0tot = t;
    __syncthreads();
    if (tid < NPB) {
      const int s = (t - v) + ((tid >= 64) ? w0tot : 0);
      st[tid] = s;
      cur[tid] = s;
    }
    __syncthreads();
  }

  // sweep 2: scatter into node-grouped order
  for (int i = tid; i < m; i += 256) {
    const int2 e = packed2[s0 + i];
    const int dl = ((uint)e.x >> 18) & (NPB - 1);
    const int pos = atomicAdd(&cur[dl], 1);
    packedN[s0 + pos] = e;
  }

  // row_start
  if (tid < NPB) {
    const int node = b * NPB + tid;
    if (node < n_nodes) row_start[node] = s0 + st[tid];
  }
  if (b == 0 && tid == 0) row_start[n_nodes] = n_edges;
}

// ---------------------------------------------------------------------------
// Aggregation (proven R8 form): 1 wave per node; lane owns 2 cols; SGPR-
// uniform edge loads; x8 unroll -> 8 independent gathers in flight.
// Fused bias + ReLU, NT float2 store.  src = e.x & 0x3FFFF.
// ---------------------------------------------------------------------------
__global__ __launch_bounds__(256) void agg_kernel(
    const ushort* __restrict__ sup, const int2* __restrict__ packed,
    const int* __restrict__ row_start, const float* __restrict__ bias,
    float* __restrict__ out, int n_nodes) {
  const int node = blockIdx.x * 4 + (threadIdx.x >> 6);
  if (node >= n_nodes) return;
  const int lane = threadIdx.x & 63;
  const int start = __builtin_amdgcn_readfirstlane(row_start[node]);
  const int end   = __builtin_amdgcn_readfirstlane(row_start[node + 1]);

  float a0 = 0.f, a1 = 0.f, b0 = 0.f, b1 = 0.f;
  float c0 = 0.f, c1 = 0.f, d0 = 0.f, d1 = 0.f;
  int i = start;
  for (; i + 7 < end; i += 8) {
    const int2 e0 = packed[i + 0];
    const int2 e1 = packed[i + 1];
    const int2 e2 = packed[i + 2];
    const int2 e3 = packed[i + 3];
    const int2 e4 = packed[i + 4];
    const int2 e5 = packed[i + 5];
    const int2 e6 = packed[i + 6];
    const int2 e7 = packed[i + 7];
    const uint u0 = *(const uint*)(sup + ((size_t)((uint)e0.x & 0x3FFFFu) << 7) + lane * 2);
    const uint u1 = *(const uint*)(sup + ((size_t)((uint)e1.x & 0x3FFFFu) << 7) + lane * 2);
    const uint u2 = *(const uint*)(sup + ((size_t)((uint)e2.x & 0x3FFFFu) << 7) + lane * 2);
    const uint u3 = *(const uint*)(sup + ((size_t)((uint)e3.x & 0x3FFFFu) << 7) + lane * 2);
    const uint u4 = *(const uint*)(sup + ((size_t)((uint)e4.x & 0x3FFFFu) << 7) + lane * 2);
    const uint u5 = *(const uint*)(sup + ((size_t)((uint)e5.x & 0x3FFFFu) << 7) + lane * 2);
    const uint u6 = *(const uint*)(sup + ((size_t)((uint)e6.x & 0x3FFFFu) << 7) + lane * 2);
    const uint u7 = *(const uint*)(sup + ((size_t)((uint)e7.x & 0x3FFFFu) << 7) + lane * 2);
    const float w0 = __int_as_float(e0.y), w1 = __int_as_float(e1.y);
    const float w2 = __int_as_float(e2.y), w3 = __int_as_float(e3.y);
    const float w4 = __int_as_float(e4.y), w5 = __int_as_float(e5.y);
    const float w6 = __int_as_float(e6.y), w7 = __int_as_float(e7.y);
    a0 += __uint_as_float(u0 << 16) * w0 + __uint_as_float(u4 << 16) * w4;
    a1 += __uint_as_float(u0 & 0xffff0000u) * w0 + __uint_as_float(u4 & 0xffff0000u) * w4;
    b0 += __uint_as_float(u1 << 16) * w1 + __uint_as_float(u5 << 16) * w5;
    b1 += __uint_as_float(u1 & 0xffff0000u) * w1 + __uint_as_float(u5 & 0xffff0000u) * w5;
    c0 += __uint_as_float(u2 << 16) * w2 + __uint_as_float(u6 << 16) * w6;
    c1 += __uint_as_float(u2 & 0xffff0000u) * w2 + __uint_as_float(u6 & 0xffff0000u) * w6;
    d0 += __uint_as_float(u3 << 16) * w3 + __uint_as_float(u7 << 16) * w7;
    d1 += __uint_as_float(u3 & 0xffff0000u) * w3 + __uint_as_float(u7 & 0xffff0000u) * w7;
  }
  for (; i + 3 < end; i += 4) {
    const int2 e0 = packed[i + 0];
    const int2 e1 = packed[i + 1];
    const int2 e2 = packed[i + 2];
    const int2 e3 = packed[i + 3];
    const uint u0 = *(const uint*)(sup + ((size_t)((uint)e0.x & 0x3FFFFu) << 7) + lane * 2);
    const uint u1 = *(const uint*)(sup + ((size_t)((uint)e1.x & 0x3FFFFu) << 7) + lane * 2);
    const uint u2 = *(const uint*)(sup + ((size_t)((uint)e2.x & 0x3FFFFu) << 7) + lane * 2);
    const uint u3 = *(const uint*)(sup + ((size_t)((uint)e3.x & 0x3FFFFu) << 7) + lane * 2);
    const float w0 = __int_as_float(e0.y), w1 = __int_as_float(e1.y);
    const float w2 = __int_as_float(e2.y), w3 = __int_as_float(e3.y);
    a0 += __uint_as_float(u0 << 16) * w0 + __uint_as_float(u2 << 16) * w2;
    a1 += __uint_as_float(u0 & 0xffff0000u) * w0 + __uint_as_float(u2 & 0xffff0000u) * w2;
    b0 += __uint_as_float(u1 << 16) * w1 + __uint_as_float(u3 << 16) * w3;
    b1 += __uint_as_float(u1 & 0xffff0000u) * w1 + __uint_as_float(u3 & 0xffff0000u) * w3;
  }
  for (; i < end; ++i) {
    const int2 e0 = packed[i];
    const uint u0 = *(const uint*)(sup + ((size_t)((uint)e0.x & 0x3FFFFu) << 7) + lane * 2);
    const float w0 = __int_as_float(e0.y);
    a0 += __uint_as_float(u0 << 16) * w0;
    a1 += __uint_as_float(u0 & 0xffff0000u) * w0;
  }

  const float2 bb = ((const float2*)bias)[lane];
  f32x2 r;
  r.x = fmaxf((a0 + b0) + (c0 + d0) + bb.x, 0.f);
  r.y = fmaxf((a1 + b1) + (c1 + d1) + bb.y, 0.f);
  __builtin_nontemporal_store(r, (f32x2*)out + (size_t)node * (NHID / 2) + lane);
}

// ---------------------------------------------------------------------------
// Fallback (ws too small): atomic scatter over bf16 support
// ---------------------------------------------------------------------------
__global__ __launch_bounds__(256) void scatter_bf16_kernel(
    const ushort* __restrict__ sup, const int* __restrict__ esrc,
    const int* __restrict__ edst, const float* __restrict__ ew,
    float* __restrict__ out, int n_edges) {
  const long long idx = (long long)blockIdx.x * 256 + threadIdx.x;
  const int e = (int)(idx >> 6);
  const int c2 = (int)(idx & 63);
  if (e >= n_edges) return;
  const int s = esrc[e];
  const int d = edst[e];
  const float wt = ew[e];
  const uint u = *(const uint*)(sup + (size_t)s * NHID + c2 * 2);
  float* drow = out + (size_t)d * NHID + c2 * 2;
  atomicAdd(drow + 0, __uint_as_float(u << 16) * wt);
  atomicAdd(drow + 1, __uint_as_float(u & 0xffff0000u) * wt);
}

__global__ __launch_bounds__(256) void bias_relu_kernel(
    float* __restrict__ out, const float* __restrict__ b, int n4) {
  const int i = blockIdx.x * 256 + threadIdx.x;
  if (i >= n4) return;
  float4 v = ((float4*)out)[i];
  const float4 bb = ((const float4*)b)[i & (NHID / 4 - 1)];
  v.x = fmaxf(v.x + bb.x, 0.f);
  v.y = fmaxf(v.y + bb.y, 0.f);
  v.z = fmaxf(v.z + bb.z, 0.f);
  v.w = fmaxf(v.w + bb.w, 0.f);
  ((float4*)out)[i] = v;
}

static inline size_t align_up(size_t v, size_t a) { return (v + a - 1) & ~(a - 1); }

extern "C" void kernel_launch(void* const* d_in, const int* in_sizes, int n_in,
                              void* d_out, int out_size, void* d_ws, size_t ws_size,
                              hipStream_t stream) {
  const float* x    = (const float*)d_in[0];
  const int*   esrc = (const int*)d_in[1];
  const int*   edst = (const int*)d_in[2];
  const float* ew   = (const float*)d_in[3];
  const float* W    = (const float*)d_in[4];
  const float* b    = (const float*)d_in[5];
  float* out = (float*)d_out;

  const int n_nodes = in_sizes[0] / NFEAT;
  const int n_edges = in_sizes[1];

  // bucket geometry: B buckets of NPB nodes; G scatter chunks, B*G <= 256K
  const int B = (n_nodes + NPB - 1) / NPB;
  int G = (n_edges + 8191) / 8192;
  const int Gmax = (256 * 1024) / (B > 0 ? B : 1);
  if (G > Gmax) G = Gmax;
  if (G < 1) G = 1;
  const int chunk = (int)align_up((size_t)(n_edges + G - 1) / G, 256);
  G = (n_edges + chunk - 1) / chunk;

  // workspace layout (~54 MB at N=100k, E=1.6M)
  char* ws = (char*)d_ws;
  size_t off = 0;
  ushort* sup       = (ushort*)(ws + off); off = align_up(off + (size_t)n_nodes * NHID * 2, 256);
  ushort* Wt        = (ushort*)(ws + off); off = align_up(off + (size_t)NFEAT * NHID * 2, 256);
  int* histT        = (int*)(ws + off);    off = align_up(off + (size_t)B * G * 4, 256);
  int* exc          = (int*)(ws + off);    off = align_up(off + (size_t)B * G * 4, 256);
  int* bsums        = (int*)(ws + off);    off = align_up(off + 1024 * 4, 256);
  int* bucket_start = (int*)(ws + off);    off = align_up(off + ((size_t)B + 1) * 4, 256);
  int* row_start    = (int*)(ws + off);    off = align_up(off + ((size_t)n_nodes + 1) * 4, 256);
  int2* packed2     = (int2*)(ws + off);   off = align_up(off + (size_t)n_edges * 8, 256);
  int2* packedN     = (int2*)(ws + off);   off = align_up(off + (size_t)n_edges * 8, 256);
  const bool csr_ok = (off <= ws_size) && (n_nodes <= 256 * 1024) && (B <= BMAX);

  const int n_gemm = (n_nodes + 63) / 64;

  if (csr_ok) {
    // 1) Wt = bf16(W^T)
    wcvt_kernel<<<(NFEAT * NHID) / 256, 256, 0, stream>>>(W, Wt);

    // 2) bucket histogram (LDS atomics only)
    hist_kernel<<<G, 256, 0, stream>>>(edst, histT, n_edges, B, G, chunk);

    // 3) scan -> per-(bucket,chunk) bases + bucket_start
    const int n_scan = B * G;
    const int nb = (n_scan + 1023) / 1024;
    scan1_kernel<<<nb, 256, 0, stream>>>(histT, exc, bsums, n_scan);
    scan2_kernel<<<1, 256, 0, stream>>>(bsums, nb);
    scan3_kernel<<<(n_scan + 255) / 256, 256, 0, stream>>>(exc, bsums, bucket_start, n_scan, G, B, n_edges);

    // 4) fused bucket-scatter || MFMA GEMM
    gemm_scatter_fused<<<n_gemm + G, 256, 0, stream>>>(
        x, Wt, sup, n_nodes, esrc, edst, ew, exc, packed2,
        n_edges, B, G, chunk, n_gemm);

    // 5) per-bucket node-grouping -> packedN + row_start (global)
    bucket_build_kernel<<<B, 256, 0, stream>>>(
        packed2, bucket_start, packedN, row_start, n_nodes, n_edges);

    // 6) full-TLP gather-sum + bias + relu
    agg_kernel<<<(n_nodes + 3) / 4, 256, 0, stream>>>(sup, packedN, row_start, b, out, n_nodes);
  } else {
    // fallback: minimal-ws path (sup + Wt only), gemm role only
    wcvt_kernel<<<(NFEAT * NHID) / 256, 256, 0, stream>>>(W, Wt);
    gemm_scatter_fused<<<n_gemm, 256, 0, stream>>>(
        x, Wt, sup, n_nodes, esrc, edst, ew, (int*)d_ws, (int2*)d_ws,
        0, 1, 0, 1, n_gemm);
    hipMemsetAsync(out, 0, (size_t)n_nodes * NHID * sizeof(float), stream);
    const long long threads = (long long)n_edges * 64;
    scatter_bf16_kernel<<<(int)((threads + 255) / 256), 256, 0, stream>>>(sup, esrc, edst, ew, out, n_edges);
    const int n4 = n_nodes * NHID / 4;
    bias_relu_kernel<<<(n4 + 255) / 256, 256, 0, stream>>>(out, b, n4);
  }
}

// Round 12
// 139.538 us; speedup vs baseline: 1.2719x; 1.0498x over previous
//
#include <hip/hip_runtime.h>
#include <hip/hip_bf16.h>

#define NFEAT 256
#define NHID  128
#define NPB   128    // nodes per bucket (dst >> 7)
#define BMAX  2048   // max buckets (n_nodes <= 256K)
#define SCHUNK 2048  // edges per scatter block (compile-time for unroll)

typedef short s16x8 __attribute__((ext_vector_type(8)));
typedef float f32x4 __attribute__((ext_vector_type(4)));
typedef float f32x2 __attribute__((ext_vector_type(2)));

static __device__ __forceinline__ ushort bfbits(float f) {
  __hip_bfloat16 h = __float2bfloat16(f);
  return *reinterpret_cast<ushort*>(&h);
}

// ---------------------------------------------------------------------------
// Prep: blocks 0..127 = W transpose+convert; blocks 128.. = bucket histogram
// via LDS atomics.  histT[b*G + g] = #edges of chunk g in bucket b.
// ---------------------------------------------------------------------------
__global__ __launch_bounds__(256) void prep_kernel(
    const float* __restrict__ W, ushort* __restrict__ Wt,
    const int* __restrict__ edst, int* __restrict__ histT,
    int n_edges, int B, int G) {
  __shared__ int hist[BMAX];
  if (blockIdx.x < 128) {
    const int id = blockIdx.x * 256 + threadIdx.x;
    const int k = id >> 7, n = id & 127;
    Wt[n * NFEAT + k] = bfbits(W[id]);
    return;
  }
  const int g = blockIdx.x - 128;
  for (int b = threadIdx.x; b < B; b += 256) hist[b] = 0;
  __syncthreads();
  const int e0 = g * SCHUNK;
  const int e1 = (e0 + SCHUNK < n_edges) ? e0 + SCHUNK : n_edges;
  for (int e = e0 + threadIdx.x; e < e1; e += 256)
    atomicAdd(&hist[(uint)edst[e] >> 7], 1);  // LDS atomic
  __syncthreads();
  for (int b = threadIdx.x; b < B; b += 256) histT[(size_t)b * G + g] = hist[b];
}

// ---------------------------------------------------------------------------
// Hierarchical exclusive scan (over histT, n = B*G, up to ~1M)
// ---------------------------------------------------------------------------
__global__ __launch_bounds__(256) void scan1_kernel(
    const int* __restrict__ in, int* __restrict__ exc,
    int* __restrict__ bsums, int n) {
  const int tid = threadIdx.x;
  const int lane = tid & 63, wid = tid >> 6;
  const int base = blockIdx.x * 1024 + tid * 4;
  int v0 = 0, v1 = 0, v2 = 0, v3 = 0;
  if (base + 3 < n) {
    int4 v = *(const int4*)(in + base);
    v0 = v.x; v1 = v.y; v2 = v.z; v3 = v.w;
  } else {
    if (base + 0 < n) v0 = in[base + 0];
    if (base + 1 < n) v1 = in[base + 1];
    if (base + 2 < n) v2 = in[base + 2];
  }
  const int tsum = v0 + v1 + v2 + v3;
  int t = tsum;
#pragma unroll
  for (int d = 1; d < 64; d <<= 1) {
    int u = __shfl_up(t, d);
    if (lane >= d) t += u;
  }
  __shared__ int wtot[4], wpre[4];
  if (lane == 63) wtot[wid] = t;
  __syncthreads();
  if (tid == 0) {
    int s = 0;
    for (int w = 0; w < 4; ++w) { wpre[w] = s; s += wtot[w]; }
    bsums[blockIdx.x] = s;
  }
  __syncthreads();
  const int off = (t - tsum) + wpre[wid];
  if (base + 0 < n) exc[base + 0] = off;
  if (base + 1 < n) exc[base + 1] = off + v0;
  if (base + 2 < n) exc[base + 2] = off + v0 + v1;
  if (base + 3 < n) exc[base + 3] = off + v0 + v1 + v2;
}

// single block, loops over bsums in chunks of 256 with running carry
__global__ __launch_bounds__(256) void scan2_kernel(int* __restrict__ bsums, int nb) {
  __shared__ int wtot[4], wpre[4], tot_s;
  const int tid = threadIdx.x;
  const int lane = tid & 63, wid = tid >> 6;
  int carry = 0;
  for (int base = 0; base < nb; base += 256) {
    const int idx = base + tid;
    const int v = (idx < nb) ? bsums[idx] : 0;
    int t = v;
#pragma unroll
    for (int d = 1; d < 64; d <<= 1) {
      int u = __shfl_up(t, d);
      if (lane >= d) t += u;
    }
    if (lane == 63) wtot[wid] = t;
    __syncthreads();
    if (tid == 0) {
      int s = 0;
      for (int w = 0; w < 4; ++w) { wpre[w] = s; s += wtot[w]; }
      tot_s = s;
    }
    __syncthreads();
    if (idx < nb) bsums[idx] = carry + (t - v) + wpre[wid];
    carry += tot_s;
    __syncthreads();
  }
}

// finalize offsets; emit bucket_start[] and transposed baseT[g*B + b]
__global__ __launch_bounds__(256) void scan3_kernel(
    const int* __restrict__ exc, const int* __restrict__ bsums,
    int* __restrict__ baseT, int* __restrict__ bucket_start,
    int n, int G, int B, int n_edges) {
  const int i = blockIdx.x * 256 + threadIdx.x;
  if (i < n) {
    const int v = exc[i] + bsums[i >> 10];
    const int b = i / G, g = i % G;
    baseT[(size_t)g * B + b] = v;
    if (g == 0) bucket_start[b] = v;
  }
  if (i == 0) bucket_start[B] = n_edges;
}

// ---------------------------------------------------------------------------
// Fused: bucket-scatter (role 0, LDS cursors, unrolled x8) || MFMA GEMM
// (role 1).  packed2: .x = src | (dst&127)<<18, .y = w bits.
// ---------------------------------------------------------------------------
__global__ __launch_bounds__(256) void gemm_scatter_fused(
    const float* __restrict__ x, const ushort* __restrict__ Wt,
    ushort* __restrict__ sup, int n_nodes,
    const int* __restrict__ esrc, const int* __restrict__ edst,
    const float* __restrict__ ew, const int* __restrict__ baseT,
    int2* __restrict__ packed2, int n_edges, int B, int G, int n_gemm) {
  __shared__ ushort As[64 * 64];   // 8 KB (scatter role aliases as cursors)
  __shared__ ushort Bs[128 * 64];  // 16 KB

  const int idx = blockIdx.x;
  const long long total = (long long)n_gemm + G;
  const int c_lo = (int)((long long)idx * G / total);
  const int c_hi = (int)(((long long)idx + 1) * G / total);
  int role, sub;
  if (c_hi > c_lo) { role = 0; sub = c_lo; }
  else             { role = 1; sub = idx - c_hi; }

  if (role == 0) {
    // ---- bucket scatter: coalesced cursor init from baseT ----
    int* cursor = (int*)As;  // up to 2048 ints
    const int g = sub;
    for (int b = threadIdx.x; b < B; b += 256) cursor[b] = baseT[(size_t)g * B + b];
    __syncthreads();
    const int e0 = g * SCHUNK;
    if (e0 + SCHUNK <= n_edges) {
      int d[8], s[8]; float w[8];
#pragma unroll
      for (int j = 0; j < 8; ++j) {
        const int e = e0 + j * 256 + threadIdx.x;
        d[j] = edst[e]; s[j] = esrc[e]; w[j] = ew[e];
      }
#pragma unroll
      for (int j = 0; j < 8; ++j) {
        const int pos = atomicAdd(&cursor[(uint)d[j] >> 7], 1);  // LDS atomic
        packed2[pos] = make_int2(s[j] | ((d[j] & (NPB - 1)) << 18), __float_as_int(w[j]));
      }
    } else {
      const int e1 = n_edges;
      for (int e = e0 + threadIdx.x; e < e1; e += 256) {
        const int dst = edst[e];
        const int pos = atomicAdd(&cursor[(uint)dst >> 7], 1);
        packed2[pos] = make_int2(esrc[e] | ((dst & (NPB - 1)) << 18), __float_as_int(ew[e]));
      }
    }
    return;
  }

  // ---- MFMA GEMM: BM=64 x NHID=128, K chunks of 64 ----
  const int t = threadIdx.x;
  const int wid = t >> 6;
  const int lane = t & 63;
  const int rowBase = sub * 64;
  if (rowBase >= n_nodes) return;

  f32x4 acc[4][2];
#pragma unroll
  for (int m = 0; m < 4; ++m)
#pragma unroll
    for (int n = 0; n < 2; ++n) acc[m][n] = (f32x4){0.f, 0.f, 0.f, 0.f};

  const float4* x4 = (const float4*)x;

  for (int kc = 0; kc < 4; ++kc) {
    __syncthreads();
#pragma unroll
    for (int it = 0; it < 4; ++it) {
      const int i4 = t + it * 256;
      const int r = i4 >> 4, k4 = i4 & 15;
      const int row = rowBase + r;
      float4 v = make_float4(0.f, 0.f, 0.f, 0.f);
      if (row < n_nodes) v = x4[(size_t)row * (NFEAT / 4) + kc * 16 + k4];
      ushort4 h;
      h.x = bfbits(v.x); h.y = bfbits(v.y); h.z = bfbits(v.z); h.w = bfbits(v.w);
      int byte = (r << 7) + (k4 << 3);
      byte ^= (r & 7) << 4;
      *(ushort4*)((char*)As + byte) = h;
    }
#pragma unroll
    for (int it = 0; it < 8; ++it) {
      const int i2 = t + it * 256;
      const int col = i2 >> 4, k4 = i2 & 15;
      const ushort4 h = *(const ushort4*)(Wt + col * NFEAT + kc * 64 + k4 * 4);
      int byte = (col << 7) + (k4 << 3);
      byte ^= (col & 7) << 4;
      *(ushort4*)((char*)Bs + byte) = h;
    }
    __syncthreads();
#pragma unroll
    for (int ks = 0; ks < 2; ++ks) {
      const int k0 = ks * 32 + (lane >> 4) * 8;
      s16x8 af[4], bfr[2];
#pragma unroll
      for (int m = 0; m < 4; ++m) {
        const int r = m * 16 + (lane & 15);
        int byte = (r << 7) + (k0 << 1);
        byte ^= (r & 7) << 4;
        af[m] = *(const s16x8*)((const char*)As + byte);
      }
#pragma unroll
      for (int n = 0; n < 2; ++n) {
        const int c = wid * 32 + n * 16 + (lane & 15);
        int byte = (c << 7) + (k0 << 1);
        byte ^= (c & 7) << 4;
        bfr[n] = *(const s16x8*)((const char*)Bs + byte);
      }
#pragma unroll
      for (int m = 0; m < 4; ++m)
#pragma unroll
        for (int n = 0; n < 2; ++n)
          acc[m][n] = __builtin_amdgcn_mfma_f32_16x16x32_bf16(af[m], bfr[n], acc[m][n], 0, 0, 0);
    }
  }

#pragma unroll
  for (int m = 0; m < 4; ++m) {
#pragma unroll
    for (int rr = 0; rr < 4; ++rr) {
      const int row = rowBase + m * 16 + (lane >> 4) * 4 + rr;
      if (row < n_nodes) {
#pragma unroll
        for (int n = 0; n < 2; ++n) {
          const int col = wid * 32 + n * 16 + (lane & 15);
          sup[(size_t)row * NHID + col] = bfbits(acc[m][n][rr]);
        }
      }
    }
  }
}

// ---------------------------------------------------------------------------
// Per-bucket node-grouping -> packedN + row_start (global); gather runs at
// full TLP in agg_kernel.
// ---------------------------------------------------------------------------
__global__ __launch_bounds__(256) void bucket_build_kernel(
    const int2* __restrict__ packed2, const int* __restrict__ bucket_start,
    int2* __restrict__ packedN, int* __restrict__ row_start,
    int n_nodes, int n_edges) {
  __shared__ int cnt[NPB];
  __shared__ int st[NPB];
  __shared__ int cur[NPB];
  __shared__ int w0tot;
  const int tid = threadIdx.x;
  const int b = blockIdx.x;
  const int s0 = bucket_start[b];
  const int s1 = bucket_start[b + 1];
  const int m = s1 - s0;

  if (tid < NPB) cnt[tid] = 0;
  __syncthreads();

  for (int i = tid; i < m; i += 256)
    atomicAdd(&cnt[((uint)packed2[s0 + i].x >> 18) & (NPB - 1)], 1);
  __syncthreads();

  {
    const int v = (tid < NPB) ? cnt[tid] : 0;
    int t = v;
#pragma unroll
    for (int d = 1; d < 64; d <<= 1) {
      int u = __shfl_up(t, d);
      if ((tid & 63) >= d) t += u;
    }
    if (tid == 63) w0tot = t;
    __syncthreads();
    if (tid < NPB) {
      const int s = (t - v) + ((tid >= 64) ? w0tot : 0);
      st[tid] = s;
      cur[tid] = s;
    }
    __syncthreads();
  }

  for (int i = tid; i < m; i += 256) {
    const int2 e = packed2[s0 + i];
    const int dl = ((uint)e.x >> 18) & (NPB - 1);
    const int pos = atomicAdd(&cur[dl], 1);
    packedN[s0 + pos] = e;
  }

  if (tid < NPB) {
    const int node = b * NPB + tid;
    if (node < n_nodes) row_start[node] = s0 + st[tid];
  }
  if (b == 0 && tid == 0) row_start[n_nodes] = n_edges;
}

// ---------------------------------------------------------------------------
// Aggregation: 1 wave per node; lane owns 2 cols; SGPR-uniform edge loads;
// x8 unroll.  Fused bias + ReLU, NT float2 store.  src = e.x & 0x3FFFF.
// ---------------------------------------------------------------------------
__global__ __launch_bounds__(256) void agg_kernel(
    const ushort* __restrict__ sup, const int2* __restrict__ packed,
    const int* __restrict__ row_start, const float* __restrict__ bias,
    float* __restrict__ out, int n_nodes) {
  const int node = blockIdx.x * 4 + (threadIdx.x >> 6);
  if (node >= n_nodes) return;
  const int lane = threadIdx.x & 63;
  const int start = __builtin_amdgcn_readfirstlane(row_start[node]);
  const int end   = __builtin_amdgcn_readfirstlane(row_start[node + 1]);

  float a0 = 0.f, a1 = 0.f, b0 = 0.f, b1 = 0.f;
  float c0 = 0.f, c1 = 0.f, d0 = 0.f, d1 = 0.f;
  int i = start;
  for (; i + 7 < end; i += 8) {
    const int2 e0 = packed[i + 0];
    const int2 e1 = packed[i + 1];
    const int2 e2 = packed[i + 2];
    const int2 e3 = packed[i + 3];
    const int2 e4 = packed[i + 4];
    const int2 e5 = packed[i + 5];
    const int2 e6 = packed[i + 6];
    const int2 e7 = packed[i + 7];
    const uint u0 = *(const uint*)(sup + ((size_t)((uint)e0.x & 0x3FFFFu) << 7) + lane * 2);
    const uint u1 = *(const uint*)(sup + ((size_t)((uint)e1.x & 0x3FFFFu) << 7) + lane * 2);
    const uint u2 = *(const uint*)(sup + ((size_t)((uint)e2.x & 0x3FFFFu) << 7) + lane * 2);
    const uint u3 = *(const uint*)(sup + ((size_t)((uint)e3.x & 0x3FFFFu) << 7) + lane * 2);
    const uint u4 = *(const uint*)(sup + ((size_t)((uint)e4.x & 0x3FFFFu) << 7) + lane * 2);
    const uint u5 = *(const uint*)(sup + ((size_t)((uint)e5.x & 0x3FFFFu) << 7) + lane * 2);
    const uint u6 = *(const uint*)(sup + ((size_t)((uint)e6.x & 0x3FFFFu) << 7) + lane * 2);
    const uint u7 = *(const uint*)(sup + ((size_t)((uint)e7.x & 0x3FFFFu) << 7) + lane * 2);
    const float w0 = __int_as_float(e0.y), w1 = __int_as_float(e1.y);
    const float w2 = __int_as_float(e2.y), w3 = __int_as_float(e3.y);
    const float w4 = __int_as_float(e4.y), w5 = __int_as_float(e5.y);
    const float w6 = __int_as_float(e6.y), w7 = __int_as_float(e7.y);
    a0 += __uint_as_float(u0 << 16) * w0 + __uint_as_float(u4 << 16) * w4;
    a1 += __uint_as_float(u0 & 0xffff0000u) * w0 + __uint_as_float(u4 & 0xffff0000u) * w4;
    b0 += __uint_as_float(u1 << 16) * w1 + __uint_as_float(u5 << 16) * w5;
    b1 += __uint_as_float(u1 & 0xffff0000u) * w1 + __uint_as_float(u5 & 0xffff0000u) * w5;
    c0 += __uint_as_float(u2 << 16) * w2 + __uint_as_float(u6 << 16) * w6;
    c1 += __uint_as_float(u2 & 0xffff0000u) * w2 + __uint_as_float(u6 & 0xffff0000u) * w6;
    d0 += __uint_as_float(u3 << 16) * w3 + __uint_as_float(u7 << 16) * w7;
    d1 += __uint_as_float(u3 & 0xffff0000u) * w3 + __uint_as_float(u7 & 0xffff0000u) * w7;
  }
  for (; i + 3 < end; i += 4) {
    const int2 e0 = packed[i + 0];
    const int2 e1 = packed[i + 1];
    const int2 e2 = packed[i + 2];
    const int2 e3 = packed[i + 3];
    const uint u0 = *(const uint*)(sup + ((size_t)((uint)e0.x & 0x3FFFFu) << 7) + lane * 2);
    const uint u1 = *(const uint*)(sup + ((size_t)((uint)e1.x & 0x3FFFFu) << 7) + lane * 2);
    const uint u2 = *(const uint*)(sup + ((size_t)((uint)e2.x & 0x3FFFFu) << 7) + lane * 2);
    const uint u3 = *(const uint*)(sup + ((size_t)((uint)e3.x & 0x3FFFFu) << 7) + lane * 2);
    const float w0 = __int_as_float(e0.y), w1 = __int_as_float(e1.y);
    const float w2 = __int_as_float(e2.y), w3 = __int_as_float(e3.y);
    a0 += __uint_as_float(u0 << 16) * w0 + __uint_as_float(u2 << 16) * w2;
    a1 += __uint_as_float(u0 & 0xffff0000u) * w0 + __uint_as_float(u2 & 0xffff0000u) * w2;
    b0 += __uint_as_float(u1 << 16) * w1 + __uint_as_float(u3 << 16) * w3;
    b1 += __uint_as_float(u1 & 0xffff0000u) * w1 + __uint_as_float(u3 & 0xffff0000u) * w3;
  }
  for (; i < end; ++i) {
    const int2 e0 = packed[i];
    const uint u0 = *(const uint*)(sup + ((size_t)((uint)e0.x & 0x3FFFFu) << 7) + lane * 2);
    const float w0 = __int_as_float(e0.y);
    a0 += __uint_as_float(u0 << 16) * w0;
    a1 += __uint_as_float(u0 & 0xffff0000u) * w0;
  }

  const float2 bb = ((const float2*)bias)[lane];
  f32x2 r;
  r.x = fmaxf((a0 + b0) + (c0 + d0) + bb.x, 0.f);
  r.y = fmaxf((a1 + b1) + (c1 + d1) + bb.y, 0.f);
  __builtin_nontemporal_store(r, (f32x2*)out + (size_t)node * (NHID / 2) + lane);
}

// ---------------------------------------------------------------------------
// Fallback (ws too small): atomic scatter over bf16 support
// ---------------------------------------------------------------------------
__global__ __launch_bounds__(256) void scatter_bf16_kernel(
    const ushort* __restrict__ sup, const int* __restrict__ esrc,
    const int* __restrict__ edst, const float* __restrict__ ew,
    float* __restrict__ out, int n_edges) {
  const long long idx = (long long)blockIdx.x * 256 + threadIdx.x;
  const int e = (int)(idx >> 6);
  const int c2 = (int)(idx & 63);
  if (e >= n_edges) return;
  const int s = esrc[e];
  const int d = edst[e];
  const float wt = ew[e];
  const uint u = *(const uint*)(sup + (size_t)s * NHID + c2 * 2);
  float* drow = out + (size_t)d * NHID + c2 * 2;
  atomicAdd(drow + 0, __uint_as_float(u << 16) * wt);
  atomicAdd(drow + 1, __uint_as_float(u & 0xffff0000u) * wt);
}

__global__ __launch_bounds__(256) void bias_relu_kernel(
    float* __restrict__ out, const float* __restrict__ b, int n4) {
  const int i = blockIdx.x * 256 + threadIdx.x;
  if (i >= n4) return;
  float4 v = ((float4*)out)[i];
  const float4 bb = ((const float4*)b)[i & (NHID / 4 - 1)];
  v.x = fmaxf(v.x + bb.x, 0.f);
  v.y = fmaxf(v.y + bb.y, 0.f);
  v.z = fmaxf(v.z + bb.z, 0.f);
  v.w = fmaxf(v.w + bb.w, 0.f);
  ((float4*)out)[i] = v;
}

static inline size_t align_up(size_t v, size_t a) { return (v + a - 1) & ~(a - 1); }

extern "C" void kernel_launch(void* const* d_in, const int* in_sizes, int n_in,
                              void* d_out, int out_size, void* d_ws, size_t ws_size,
                              hipStream_t stream) {
  const float* x    = (const float*)d_in[0];
  const int*   esrc = (const int*)d_in[1];
  const int*   edst = (const int*)d_in[2];
  const float* ew   = (const float*)d_in[3];
  const float* W    = (const float*)d_in[4];
  const float* b    = (const float*)d_in[5];
  float* out = (float*)d_out;

  const int n_nodes = in_sizes[0] / NFEAT;
  const int n_edges = in_sizes[1];

  // bucket geometry: B buckets of NPB nodes; G scatter chunks of SCHUNK
  const int B = (n_nodes + NPB - 1) / NPB;
  const int G = (n_edges + SCHUNK - 1) / SCHUNK;
  const long long n_scan_ll = (long long)B * G;

  // workspace layout (~63 MB at N=100k, E=1.6M)
  char* ws = (char*)d_ws;
  size_t off = 0;
  ushort* sup       = (ushort*)(ws + off); off = align_up(off + (size_t)n_nodes * NHID * 2, 256);
  ushort* Wt        = (ushort*)(ws + off); off = align_up(off + (size_t)NFEAT * NHID * 2, 256);
  int* histT        = (int*)(ws + off);    off = align_up(off + (size_t)B * G * 4, 256);
  int* exc          = (int*)(ws + off);    off = align_up(off + (size_t)B * G * 4, 256);
  int* baseT        = (int*)(ws + off);    off = align_up(off + (size_t)B * G * 4, 256);
  int* bsums        = (int*)(ws + off);    off = align_up(off + 1024 * 4, 256);
  int* bucket_start = (int*)(ws + off);    off = align_up(off + ((size_t)B + 1) * 4, 256);
  int* row_start    = (int*)(ws + off);    off = align_up(off + ((size_t)n_nodes + 1) * 4, 256);
  int2* packed2     = (int2*)(ws + off);   off = align_up(off + (size_t)n_edges * 8, 256);
  int2* packedN     = (int2*)(ws + off);   off = align_up(off + (size_t)n_edges * 8, 256);
  const bool csr_ok = (off <= ws_size) && (n_nodes <= 256 * 1024) && (B <= BMAX) &&
                      (n_scan_ll <= 1024 * 1024);

  const int n_gemm = (n_nodes + 63) / 64;

  if (csr_ok) {
    // 1) prep: Wt = bf16(W^T)  ||  bucket histogram
    prep_kernel<<<128 + G, 256, 0, stream>>>(W, Wt, edst, histT, n_edges, B, G);

    // 2) scan -> baseT (transposed) + bucket_start
    const int n_scan = (int)n_scan_ll;
    const int nb = (n_scan + 1023) / 1024;
    scan1_kernel<<<nb, 256, 0, stream>>>(histT, exc, bsums, n_scan);
    scan2_kernel<<<1, 256, 0, stream>>>(bsums, nb);
    scan3_kernel<<<(n_scan + 255) / 256, 256, 0, stream>>>(exc, bsums, baseT, bucket_start, n_scan, G, B, n_edges);

    // 3) fused bucket-scatter || MFMA GEMM
    gemm_scatter_fused<<<n_gemm + G, 256, 0, stream>>>(
        x, Wt, sup, n_nodes, esrc, edst, ew, baseT, packed2, n_edges, B, G, n_gemm);

    // 4) per-bucket node-grouping -> packedN + row_start
    bucket_build_kernel<<<B, 256, 0, stream>>>(
        packed2, bucket_start, packedN, row_start, n_nodes, n_edges);

    // 5) full-TLP gather-sum + bias + relu
    agg_kernel<<<(n_nodes + 3) / 4, 256, 0, stream>>>(sup, packedN, row_start, b, out, n_nodes);
  } else {
    // fallback: minimal-ws path (sup + Wt only), gemm role only
    prep_kernel<<<128, 256, 0, stream>>>(W, Wt, edst, (int*)d_ws, 0, 1, 1);
    gemm_scatter_fused<<<n_gemm, 256, 0, stream>>>(
        x, Wt, sup, n_nodes, esrc, edst, ew, (int*)d_ws, (int2*)d_ws,
        0, 1, 0, n_gemm);
    hipMemsetAsync(out, 0, (size_t)n_nodes * NHID * sizeof(float), stream);
    const long long threads = (long long)n_edges * 64;
    scatter_bf16_kernel<<<(int)((threads + 255) / 256), 256, 0, stream>>>(sup, esrc, edst, ew, out, n_edges);
    const int n4 = n_nodes * NHID / 4;
    bias_relu_kernel<<<(n4 + 255) / 256, 256, 0, stream>>>(out, b, n4);
  }
}